// Round 2
// baseline (223.789 us; speedup 1.0000x reference)
//
#include <hip/hip_runtime.h>

#define B_   8
#define N_   307
#define BN   (B_ * N_)          // 2456 blocks
#define OUT_ELEMS (BN * 64 * 64)

typedef float f32x4 __attribute__((ext_vector_type(4)));
typedef short s16x8 __attribute__((ext_vector_type(8)));

__device__ __forceinline__ unsigned short f2bf(float x) {
    unsigned int u = __builtin_bit_cast(unsigned int, x);
    u += 0x7FFFu + ((u >> 16) & 1u);        // round-to-nearest-even
    return (unsigned short)(u >> 16);
}

// XOR-swizzle on 16B frag rows (G4 / m201): bijective within 64-row groups.
__device__ __forceinline__ int swz(int row) { return row ^ ((row >> 3) & 7); }

__device__ __forceinline__ s16x8 ldfrag(const unsigned short* p) {
    return *reinterpret_cast<const s16x8*>(p);
}

__device__ __forceinline__ s16x8 cvt8(float4 lo, float4 hi) {
    s16x8 f;
    f[0] = (short)f2bf(lo.x); f[1] = (short)f2bf(lo.y);
    f[2] = (short)f2bf(lo.z); f[3] = (short)f2bf(lo.w);
    f[4] = (short)f2bf(hi.x); f[5] = (short)f2bf(hi.y);
    f[6] = (short)f2bf(hi.z); f[7] = (short)f2bf(hi.w);
    return f;
}

// W (64x64 row-major fp32, regs) -> bf16 B-operand frag layout in LDS (swizzled)
__device__ __forceinline__ void writeW(const float4 wv[4], unsigned short* dst, int tid) {
#pragma unroll
    for (int i = 0; i < 4; ++i) {
        int idx = i * 256 + tid;
        float4 v = wv[i];
        int k  = idx >> 4;
        int n0 = (idx & 15) << 2;
        int ki = k >> 5;
        int qd = (k >> 3) & 3;
        int j  = k & 7;
        float vvv[4] = {v.x, v.y, v.z, v.w};
#pragma unroll
        for (int c = 0; c < 4; ++c) {
            int n = n0 + c;
            int row = ((n >> 4) * 2 + ki) * 64 + (qd << 4) + (n & 15);
            dst[(swz(row) << 3) + j] = f2bf(vvv[c]);
        }
    }
}

__global__ __launch_bounds__(256, 5) void mta_kernel(
    const float* __restrict__ Xq, const float* __restrict__ Xk,
    const float* __restrict__ Xv, const float* __restrict__ maskp,
    const float* __restrict__ res, const float* __restrict__ Wq,
    const float* __restrict__ Wk, const float* __restrict__ Wv,
    const float* __restrict__ Wfc, const float* __restrict__ lnS,
    const float* __restrict__ lnB, float* __restrict__ out,
    float* __restrict__ scores_out)
{
    // 32KB LDS exactly -> 5 blocks/CU (was 40KB -> 4). stage_A removed (A-frags
    // load direct from global); softmax cross-wave combine removed (k-tiled waves).
    __shared__ __align__(16) unsigned char smem[32768];
    unsigned short* sKf = (unsigned short*)(smem);           // 8KB scores B-frags (K)
    unsigned short* sQf = (unsigned short*)(smem + 8192);    // 8KB scores A-frags (Q) / ctx frags (fc)
    unsigned short* sVf = (unsigned short*)(smem + 16384);   // 8KB PV B-frags (V)
    unsigned short* sWA = (unsigned short*)(smem + 24576);   // 8KB W frags / attn A-frags

    const int bn   = blockIdx.x;
    const int tid  = threadIdx.x;
    const int w    = tid >> 6;
    const int lane = tid & 63;
    const int quad = lane >> 4;
    const int l16  = lane & 15;
    const size_t base64 = (size_t)bn * 4096;

    // per-lane (q-tiled) offsets + mask bits, head-invariant. q = mt*16+quad*4+r,
    // col = w*16+l16 (k-tiled score layout).
    int  qoff[4][4];
    bool bm[4][4];
#pragma unroll
    for (int mt = 0; mt < 4; ++mt) {
        float4 mv = *reinterpret_cast<const float4*>(maskp + bn * 64 + mt * 16 + quad * 4);
        float mvv[4] = {mv.x, mv.y, mv.z, mv.w};
#pragma unroll
        for (int r = 0; r < 4; ++r) {
            qoff[mt][r] = (mt * 16 + quad * 4 + r) * 64 + w * 16 + l16;
            bm[mt][r]   = mvv[r] > 0.5f;
        }
    }

    // prefetch res_att for head 0 (lands during projections)
    float resv[2][4][4];
    {
        const size_t sb0 = ((size_t)(bn * 4)) << 12;
#pragma unroll
        for (int mt = 0; mt < 4; ++mt)
#pragma unroll
            for (int r = 0; r < 4; ++r)
                resv[0][mt][r] = res[sb0 + qoff[mt][r]];
    }

    // ---------------- Projections: Q (scaled 1/4), K, V ----------------
    // A-frags direct from global: lane holds X[m = w*16+l16][k = quad*8 + ki*32 ..+7]
    float4 xa[3][4], wv[3][4];
    {
        const float* p = Xq + base64 + (w * 16 + l16) * 64 + quad * 8;
        xa[0][0] = *(const float4*)(p);      xa[0][1] = *(const float4*)(p + 4);
        xa[0][2] = *(const float4*)(p + 32); xa[0][3] = *(const float4*)(p + 36);
        const float4* w4 = (const float4*)Wq;
#pragma unroll
        for (int i = 0; i < 4; ++i) wv[0][i] = w4[i * 256 + tid];
    }
#pragma unroll
    for (int pj = 0; pj < 3; ++pj) {
        writeW(wv[pj], sWA, tid);
        if (pj < 2) {                        // prefetch next proj's X + W
            const float* Xn = (pj == 0) ? Xk : Xv;
            const float* Wn = (pj == 0) ? Wk : Wv;
            const float* p = Xn + base64 + (w * 16 + l16) * 64 + quad * 8;
            xa[pj + 1][0] = *(const float4*)(p);      xa[pj + 1][1] = *(const float4*)(p + 4);
            xa[pj + 1][2] = *(const float4*)(p + 32); xa[pj + 1][3] = *(const float4*)(p + 36);
            const float4* w4 = (const float4*)Wn;
#pragma unroll
            for (int i = 0; i < 4; ++i) wv[pj + 1][i] = w4[i * 256 + tid];
        }
        __syncthreads();
        s16x8 a0 = cvt8(xa[pj][0], xa[pj][1]);
        s16x8 a1 = cvt8(xa[pj][2], xa[pj][3]);
#pragma unroll
        for (int nt = 0; nt < 4; ++nt) {
            f32x4 acc = {0.f, 0.f, 0.f, 0.f};
            s16x8 b0 = ldfrag(sWA + (swz((nt * 2 + 0) * 64 + lane) << 3));
            s16x8 b1 = ldfrag(sWA + (swz((nt * 2 + 1) * 64 + lane) << 3));
            acc = __builtin_amdgcn_mfma_f32_16x16x32_bf16(a0, b0, acc, 0, 0, 0);
            acc = __builtin_amdgcn_mfma_f32_16x16x32_bf16(a1, b1, acc, 0, 0, 0);
            if (pj == 0) {          // Q -> scores A-frag layout, fold 1/sqrt(16)
#pragma unroll
                for (int r = 0; r < 4; ++r) {
                    int rowq = (nt * 4 + w) * 32 + ((l16 >> 3) << 4) + quad * 4 + r;
                    sQf[(swz(rowq) << 3) + (l16 & 7)] = f2bf(acc[r] * 0.25f);
                }
            } else if (pj == 1) {   // K -> scores B-frag layout
#pragma unroll
                for (int r = 0; r < 4; ++r) {
                    int rowk = (nt * 4 + w) * 32 + ((l16 >> 3) << 4) + quad * 4 + r;
                    sKf[(swz(rowk) << 3) + (l16 & 7)] = f2bf(acc[r]);
                }
            } else {                // V -> PV B-frag layout (nt == head)
#pragma unroll
                for (int r = 0; r < 4; ++r) {
                    int kk = w * 16 + quad * 4 + r;
                    int rowv = (nt * 2 + (kk >> 5)) * 64 + (((kk >> 3) & 3) << 4) + l16;
                    sVf[(swz(rowv) << 3) + (kk & 7)] = f2bf(acc[r]);
                }
            }
        }
        __syncthreads();
    }

    // ---------------- Attention (k-tiled waves: wave w owns score cols w*16..+15) ----------------
    f32x4 ctx[4];
#pragma unroll
    for (int h = 0; h < 4; ++h) ctx[h] = {0.f, 0.f, 0.f, 0.f};

    const s16x8 zf = {0, 0, 0, 0, 0, 0, 0, 0};
#pragma unroll
    for (int h = 0; h < 4; ++h) {
        const size_t sbase = ((size_t)(bn * 4 + h)) << 12;
        if (h < 3) {                         // prefetch next head's res_att
            const size_t nb = sbase + 4096;
#pragma unroll
            for (int mt = 0; mt < 4; ++mt)
#pragma unroll
                for (int r = 0; r < 4; ++r)
                    resv[(h + 1) & 1][mt][r] = res[nb + qoff[mt][r]];
        }

        // scores: B-frag = K tile w (fixed), loop A over q-mtiles. K=16 zero-padded.
        s16x8 bk = zf;
        if (lane < 32) bk = ldfrag(sKf + (swz((h * 4 + w) * 32 + lane) << 3));
        float sv[4][4];
#pragma unroll
        for (int mt = 0; mt < 4; ++mt) {
            s16x8 aq = zf;
            if (lane < 32) aq = ldfrag(sQf + (swz((h * 4 + mt) * 32 + lane) << 3));
            f32x4 t = {0.f, 0.f, 0.f, 0.f};
            t = __builtin_amdgcn_mfma_f32_16x16x32_bf16(aq, bk, t, 0, 0, 0);
#pragma unroll
            for (int r = 0; r < 4; ++r) {
                float s = t[r] + resv[h & 1][mt][r];
                s = bm[mt][r] ? -1e9f : s;
                scores_out[sbase + qoff[mt][r]] = s;   // coalesced 64B segments
                sv[mt][r] = s;
            }
        }

        // softmax over q: fully in-wave (16 in-thread + cross-quad shfl)
        float mx = -3.0e38f;
#pragma unroll
        for (int mt = 0; mt < 4; ++mt)
#pragma unroll
            for (int r = 0; r < 4; ++r) mx = fmaxf(mx, sv[mt][r]);
        mx = fmaxf(mx, __shfl_xor(mx, 16, 64));
        mx = fmaxf(mx, __shfl_xor(mx, 32, 64));
        float ss = 0.f;
#pragma unroll
        for (int mt = 0; mt < 4; ++mt)
#pragma unroll
            for (int r = 0; r < 4; ++r) {
                float e = __expf(sv[mt][r] - mx);
                sv[mt][r] = e; ss += e;
            }
        ss += __shfl_xor(ss, 16, 64);
        ss += __shfl_xor(ss, 32, 64);
        float inv = 1.0f / ss;

        // attn -> PV A-frag layout (q = mt*16+quad*4+r, k = w*16+l16)
#pragma unroll
        for (int mt = 0; mt < 4; ++mt) {
            int rw = (mt * 2 + (w >> 1)) * 64 + ((w & 1) * 2 + (l16 >> 3)) * 16 + quad * 4;
#pragma unroll
            for (int r = 0; r < 4; ++r)
                sWA[(swz(rw + r) << 3) + (l16 & 7)] = f2bf(sv[mt][r] * inv);
        }
        __syncthreads();

        // PV: ctx_h += attn · V_h   (wave w owns q-mtile w again)
#pragma unroll
        for (int ki = 0; ki < 2; ++ki) {
            s16x8 ap = ldfrag(sWA + (swz((w * 2 + ki) * 64 + lane) << 3));
            s16x8 bv = ldfrag(sVf + (swz((h * 2 + ki) * 64 + lane) << 3));
            ctx[h] = __builtin_amdgcn_mfma_f32_16x16x32_bf16(ap, bv, ctx[h], 0, 0, 0);
        }
        __syncthreads();   // protect sWA (next head) / sQf+sWA (fc)
    }

    // ---------------- fc + residual + layernorm ----------------
    float4 wfc[4];
    {
        const float4* w4 = (const float4*)Wfc;
#pragma unroll
        for (int i = 0; i < 4; ++i) wfc[i] = w4[i * 256 + tid];
    }
    float xres[4][4];
#pragma unroll
    for (int nt = 0; nt < 4; ++nt)
#pragma unroll
        for (int r = 0; r < 4; ++r)
            xres[nt][r] = Xq[base64 + (w * 16 + quad * 4 + r) * 64 + nt * 16 + l16];

    // ctx -> fc A-frag layout (into sQf region, dead after attention)
#pragma unroll
    for (int h = 0; h < 4; ++h) {
        int c    = h * 16 + l16;
        int rowb = (w * 2 + (c >> 5)) * 64 + (((c >> 3) & 3) << 4) + quad * 4;
#pragma unroll
        for (int r = 0; r < 4; ++r)
            sQf[(swz(rowb + r) << 3) + (c & 7)] = f2bf(ctx[h][r]);
    }
    writeW(wfc, sWA, tid);
    __syncthreads();

    f32x4 oacc[4];
    {
        s16x8 a0 = ldfrag(sQf + (swz((w * 2 + 0) * 64 + lane) << 3));
        s16x8 a1 = ldfrag(sQf + (swz((w * 2 + 1) * 64 + lane) << 3));
#pragma unroll
        for (int nt = 0; nt < 4; ++nt) {
            f32x4 acc = {0.f, 0.f, 0.f, 0.f};
            s16x8 b0 = ldfrag(sWA + (swz((nt * 2 + 0) * 64 + lane) << 3));
            s16x8 b1 = ldfrag(sWA + (swz((nt * 2 + 1) * 64 + lane) << 3));
            acc = __builtin_amdgcn_mfma_f32_16x16x32_bf16(a0, b0, acc, 0, 0, 0);
            acc = __builtin_amdgcn_mfma_f32_16x16x32_bf16(a1, b1, acc, 0, 0, 0);
            oacc[nt] = acc;
        }
    }

    float scl[4], bia[4];
#pragma unroll
    for (int nt = 0; nt < 4; ++nt) {
        scl[nt] = lnS[nt * 16 + l16];
        bia[nt] = lnB[nt * 16 + l16];
    }
#pragma unroll
    for (int r = 0; r < 4; ++r) {
        int q = w * 16 + quad * 4 + r;
        float px[4], sum = 0.f, sq = 0.f;
#pragma unroll
        for (int nt = 0; nt < 4; ++nt) {
            float x = oacc[nt][r] + xres[nt][r];
            px[nt] = x; sum += x; sq += x * x;
        }
#pragma unroll
        for (int m = 1; m <= 8; m <<= 1) {
            sum += __shfl_xor(sum, m, 64);
            sq  += __shfl_xor(sq,  m, 64);
        }
        float mu   = sum * 0.015625f;
        float var  = sq * 0.015625f - mu * mu;
        float rstd = rsqrtf(var + 1e-5f);
#pragma unroll
        for (int nt = 0; nt < 4; ++nt) {
            out[base64 + q * 64 + nt * 16 + l16] = (px[nt] - mu) * rstd * scl[nt] + bia[nt];
        }
    }
}

extern "C" void kernel_launch(void* const* d_in, const int* in_sizes, int n_in,
                              void* d_out, int out_size, void* d_ws, size_t ws_size,
                              hipStream_t stream) {
    const float* Xq   = (const float*)d_in[0];
    const float* Xk   = (const float*)d_in[1];
    const float* Xv   = (const float*)d_in[2];
    const float* msk  = (const float*)d_in[3];
    const float* res  = (const float*)d_in[4];
    const float* Wq   = (const float*)d_in[5];
    const float* Wk   = (const float*)d_in[6];
    const float* Wv   = (const float*)d_in[7];
    const float* Wfc  = (const float*)d_in[8];
    const float* lnS  = (const float*)d_in[9];
    const float* lnB  = (const float*)d_in[10];
    float* out    = (float*)d_out;
    float* scores = out + OUT_ELEMS;
    mta_kernel<<<BN, 256, 0, stream>>>(Xq, Xk, Xv, msk, res, Wq, Wk, Wv, Wfc,
                                       lnS, lnB, out, scores);
}

// Round 4
// 184.483 us; speedup vs baseline: 1.2131x; 1.2131x over previous
//
#include <hip/hip_runtime.h>

#define B_   8
#define N_   307
#define BN   (B_ * N_)          // 2456 blocks
#define OUT_ELEMS (BN * 64 * 64)

typedef float f32x4 __attribute__((ext_vector_type(4)));
typedef short s16x8 __attribute__((ext_vector_type(8)));

__device__ __forceinline__ unsigned short f2bf(float x) {
    unsigned int u = __builtin_bit_cast(unsigned int, x);
    u += 0x7FFFu + ((u >> 16) & 1u);        // round-to-nearest-even
    return (unsigned short)(u >> 16);
}

// XOR-swizzle on 16B frag rows (G4 / m201): bijective within 8-row groups.
__device__ __forceinline__ int swz(int row) { return row ^ ((row >> 3) & 7); }

__device__ __forceinline__ s16x8 ldfrag(const unsigned short* p) {
    return *reinterpret_cast<const s16x8*>(p);
}

__device__ __forceinline__ s16x8 cvt8(float4 lo, float4 hi) {
    s16x8 f;
    f[0] = (short)f2bf(lo.x); f[1] = (short)f2bf(lo.y);
    f[2] = (short)f2bf(lo.z); f[3] = (short)f2bf(lo.w);
    f[4] = (short)f2bf(hi.x); f[5] = (short)f2bf(hi.y);
    f[6] = (short)f2bf(hi.z); f[7] = (short)f2bf(hi.w);
    return f;
}

// 64x64 row-major fp32 (K x N) global -> bf16 B-operand frag layout (swizzled)
__device__ __forceinline__ void stage_B(const float* __restrict__ src,
                                        unsigned short* dst, int tid) {
    const float4* s4 = reinterpret_cast<const float4*>(src);
#pragma unroll
    for (int i = 0; i < 4; ++i) {
        int idx = i * 256 + tid;
        float4 v = s4[idx];
        int k  = idx >> 4;
        int n0 = (idx & 15) << 2;
        int ki = k >> 5;
        int qd = (k >> 3) & 3;
        int j  = k & 7;
        float vv[4] = {v.x, v.y, v.z, v.w};
#pragma unroll
        for (int c = 0; c < 4; ++c) {
            int n = n0 + c;
            int row = ((n >> 4) * 2 + ki) * 64 + (qd << 4) + (n & 15);
            dst[(swz(row) << 3) + j] = f2bf(vv[c]);
        }
    }
}

__global__ __launch_bounds__(256, 5) void mta_kernel(
    const float* __restrict__ Xq, const float* __restrict__ Xk,
    const float* __restrict__ Xv, const float* __restrict__ maskp,
    const float* __restrict__ res, const float* __restrict__ Wq,
    const float* __restrict__ Wk, const float* __restrict__ Wv,
    const float* __restrict__ Wfc, const float* __restrict__ lnS,
    const float* __restrict__ lnB, float* __restrict__ out,
    float* __restrict__ scores_out)
{
    // 32KB exactly -> 5 blocks/CU. Attention layout is R1's q-row-tiled
    // (coalesced complete 256B rows for res reads / scores writes).
    // Softmax: no max-sub (scores bounded; masked -1e9 -> exp underflow 0),
    // so cross-wave combine is a 1KB column-sum buffer aliased into dead LDS:
    //   head 0   -> sWA first 1KB (extra barrier before frag writes)
    //   head h>0 -> sKf region of head h-1 (2KB, dead since h-1's combine barrier)
    __shared__ __align__(16) unsigned char smem[32768];
    unsigned short* sKf = (unsigned short*)(smem);           // 8KB scores B-frags (K)
    unsigned short* sQf = (unsigned short*)(smem + 8192);    // 8KB scores A-frags (Q) / ctx frags (fc)
    unsigned short* sVf = (unsigned short*)(smem + 16384);   // 8KB PV B-frags (V)
    unsigned short* sWA = (unsigned short*)(smem + 24576);   // 8KB W frags / attn A-frags

    const int bn   = blockIdx.x;
    const int tid  = threadIdx.x;
    const int w    = tid >> 6;
    const int lane = tid & 63;
    const int quad = lane >> 4;
    const int l16  = lane & 15;
    const size_t base64 = (size_t)bn * 4096;

    // q-tiled per-lane tile offset: element (q = w*16+quad*4+r, col = nt*16+l16)
    // sits at toff + r*64 + nt*16 (imm-foldable).
    const int toff = (w * 16 + quad * 4) * 64 + l16;

    // mask bits for this thread's 4 q-rows
    float4 mv = *reinterpret_cast<const float4*>(maskp + bn * 64 + w * 16 + quad * 4);
    bool bm[4] = {mv.x > 0.5f, mv.y > 0.5f, mv.z > 0.5f, mv.w > 0.5f};

    // res double-buffer; prefetch head 0 now (lands under projections)
    float rA[4][4], rB[4][4];
    {
        const float* rp = res + (((size_t)(bn * 4)) << 12) + toff;
#pragma unroll
        for (int nt = 0; nt < 4; ++nt)
#pragma unroll
            for (int r = 0; r < 4; ++r)
                rA[nt][r] = rp[r * 64 + nt * 16];
    }

    // ---------------- Projections: Q (scaled 1/4), K, V ----------------
#pragma unroll 1
    for (int pj = 0; pj < 3; ++pj) {
        const float* Xs = (pj == 0) ? Xq : (pj == 1) ? Xk : Xv;
        const float* Ws = (pj == 0) ? Wq : (pj == 1) ? Wk : Wv;
        // A-frags direct from global: lane holds X[m=w*16+l16][k=quad*8+ki*32 ..+7]
        const float* p = Xs + base64 + (w * 16 + l16) * 64 + quad * 8;
        float4 x0 = *(const float4*)(p);      float4 x1 = *(const float4*)(p + 4);
        float4 x2 = *(const float4*)(p + 32); float4 x3 = *(const float4*)(p + 36);
        stage_B(Ws, sWA, tid);
        __syncthreads();
        s16x8 a0 = cvt8(x0, x1);
        s16x8 a1 = cvt8(x2, x3);
#pragma unroll
        for (int nt = 0; nt < 4; ++nt) {
            f32x4 acc = {0.f, 0.f, 0.f, 0.f};
            s16x8 b0 = ldfrag(sWA + (swz((nt * 2 + 0) * 64 + lane) << 3));
            s16x8 b1 = ldfrag(sWA + (swz((nt * 2 + 1) * 64 + lane) << 3));
            acc = __builtin_amdgcn_mfma_f32_16x16x32_bf16(a0, b0, acc, 0, 0, 0);
            acc = __builtin_amdgcn_mfma_f32_16x16x32_bf16(a1, b1, acc, 0, 0, 0);
            if (pj == 0) {          // Q -> scores A-frag layout, fold 1/sqrt(16)
#pragma unroll
                for (int r = 0; r < 4; ++r) {
                    int rowq = (nt * 4 + w) * 32 + ((l16 >> 3) << 4) + quad * 4 + r;
                    sQf[(swz(rowq) << 3) + (l16 & 7)] = f2bf(acc[r] * 0.25f);
                }
            } else if (pj == 1) {   // K -> scores B-frag layout
#pragma unroll
                for (int r = 0; r < 4; ++r) {
                    int rowk = (nt * 4 + w) * 32 + ((l16 >> 3) << 4) + quad * 4 + r;
                    sKf[(swz(rowk) << 3) + (l16 & 7)] = f2bf(acc[r]);
                }
            } else {                // V -> PV B-frag layout (nt == head)
#pragma unroll
                for (int r = 0; r < 4; ++r) {
                    int kk = w * 16 + quad * 4 + r;
                    int rowv = (nt * 2 + (kk >> 5)) * 64 + (((kk >> 3) & 3) << 4) + l16;
                    sVf[(swz(rowv) << 3) + (kk & 7)] = f2bf(acc[r]);
                }
            }
        }
        __syncthreads();
    }

    // ---------------- Attention (q-row-tiled waves; full rows coalesced) ----------------
    f32x4 ctx[4];
#pragma unroll
    for (int h = 0; h < 4; ++h) ctx[h] = {0.f, 0.f, 0.f, 0.f};

    const s16x8 zf = {0, 0, 0, 0, 0, 0, 0, 0};
#pragma unroll
    for (int h = 0; h < 4; ++h) {
        const size_t sbase = ((size_t)(bn * 4 + h)) << 12;
        float (&rc)[4][4] = (h & 1) ? rB : rA;   // current head's res
        float (&rn)[4][4] = (h & 1) ? rA : rB;   // next head's res
        if (h < 3) {
            const float* rp = res + sbase + 4096 + toff;
#pragma unroll
            for (int nt = 0; nt < 4; ++nt)
#pragma unroll
                for (int r = 0; r < 4; ++r)
                    rn[nt][r] = rp[r * 64 + nt * 16];
        }

        // scores tile rows w*16..+15: A = Q tile w, loop B over k-ntiles. K=16 zero-padded.
        s16x8 aq = zf;
        if (lane < 32) aq = ldfrag(sQf + (swz((h * 4 + w) * 32 + lane) << 3));
        float sv[4][4], Sw[4];
#pragma unroll
        for (int nt = 0; nt < 4; ++nt) {
            s16x8 bk = zf;
            if (lane < 32) bk = ldfrag(sKf + (swz((h * 4 + nt) * 32 + lane) << 3));
            f32x4 t = {0.f, 0.f, 0.f, 0.f};
            t = __builtin_amdgcn_mfma_f32_16x16x32_bf16(aq, bk, t, 0, 0, 0);
#pragma unroll
            for (int r = 0; r < 4; ++r) {
                float s = t[r] + rc[nt][r];
                s = bm[r] ? -1e9f : s;
                // never re-read: keep out of L2/LLC
                __builtin_nontemporal_store(s, scores_out + sbase + toff + r * 64 + nt * 16);
                sv[nt][r] = __expf(s);      // masked rows -> exp underflows to 0
            }
            // per-column (k = nt*16+l16) partial sum over this wave's 16 q rows
            float e = sv[nt][0] + sv[nt][1] + sv[nt][2] + sv[nt][3];
            e += __shfl_xor(e, 16, 64);
            e += __shfl_xor(e, 32, 64);
            Sw[nt] = e;
        }
        float* wS = (h == 0) ? (float*)(smem + 24576) : (float*)(smem + (h - 1) * 2048);
        if (quad == 0) {
#pragma unroll
            for (int nt = 0; nt < 4; ++nt) wS[(nt * 16 + l16) * 4 + w] = Sw[nt];
        }
        __syncthreads();   // combine barrier (also orders prev head's PV reads of sWA)

        float inv[4];
#pragma unroll
        for (int nt = 0; nt < 4; ++nt) {
            float4 vs = *reinterpret_cast<float4*>(&wS[(nt * 16 + l16) * 4]);
            inv[nt] = 1.0f / (vs.x + vs.y + vs.z + vs.w + 1e-30f);
        }
        if (h == 0) __syncthreads();   // wS aliases sWA only at head 0

        // attn -> PV A-frag layout (q = w*16+quad*4+r, k = nt*16+l16)
#pragma unroll
        for (int nt = 0; nt < 4; ++nt) {
            int k  = nt * 16 + l16;
            int rw = (w * 2 + (k >> 5)) * 64 + (((k >> 3) & 3) << 4) + quad * 4;
#pragma unroll
            for (int r = 0; r < 4; ++r)
                sWA[(swz(rw + r) << 3) + (k & 7)] = f2bf(sv[nt][r] * inv[nt]);
        }
        __syncthreads();

        // PV: ctx_h += attn · V_h
#pragma unroll
        for (int ki = 0; ki < 2; ++ki) {
            s16x8 ap = ldfrag(sWA + (swz((w * 2 + ki) * 64 + lane) << 3));
            s16x8 bv = ldfrag(sVf + (swz((h * 2 + ki) * 64 + lane) << 3));
            ctx[h] = __builtin_amdgcn_mfma_f32_16x16x32_bf16(ap, bv, ctx[h], 0, 0, 0);
        }
        // no trailing barrier: next head's combine barrier orders sWA reuse
    }
    __syncthreads();   // protect sWA (Wfc staging) + sQf (ctx frags) after last PV

    // ---------------- fc + residual + layernorm ----------------
    float xres[4][4];
    {
        const float* xp = Xq + base64 + toff;
#pragma unroll
        for (int nt = 0; nt < 4; ++nt)
#pragma unroll
            for (int r = 0; r < 4; ++r)
                xres[nt][r] = xp[r * 64 + nt * 16];
    }
    // ctx -> fc A-frag layout (into sQf, dead after attention)
#pragma unroll
    for (int hh = 0; hh < 4; ++hh) {
        int c    = hh * 16 + l16;
        int rowb = (w * 2 + (c >> 5)) * 64 + (((c >> 3) & 3) << 4) + quad * 4;
#pragma unroll
        for (int r = 0; r < 4; ++r)
            sQf[(swz(rowb + r) << 3) + (c & 7)] = f2bf(ctx[hh][r]);
    }
    stage_B(Wfc, sWA, tid);
    __syncthreads();

    f32x4 oacc[4];
    {
        s16x8 a0 = ldfrag(sQf + (swz((w * 2 + 0) * 64 + lane) << 3));
        s16x8 a1 = ldfrag(sQf + (swz((w * 2 + 1) * 64 + lane) << 3));
#pragma unroll
        for (int nt = 0; nt < 4; ++nt) {
            f32x4 acc = {0.f, 0.f, 0.f, 0.f};
            s16x8 b0 = ldfrag(sWA + (swz((nt * 2 + 0) * 64 + lane) << 3));
            s16x8 b1 = ldfrag(sWA + (swz((nt * 2 + 1) * 64 + lane) << 3));
            acc = __builtin_amdgcn_mfma_f32_16x16x32_bf16(a0, b0, acc, 0, 0, 0);
            acc = __builtin_amdgcn_mfma_f32_16x16x32_bf16(a1, b1, acc, 0, 0, 0);
            oacc[nt] = acc;
        }
    }

    float scl[4], bia[4];
#pragma unroll
    for (int nt = 0; nt < 4; ++nt) {
        scl[nt] = lnS[nt * 16 + l16];
        bia[nt] = lnB[nt * 16 + l16];
    }
#pragma unroll
    for (int r = 0; r < 4; ++r) {
        float px[4], sum = 0.f, sq = 0.f;
#pragma unroll
        for (int nt = 0; nt < 4; ++nt) {
            float x = oacc[nt][r] + xres[nt][r];
            px[nt] = x; sum += x; sq += x * x;
        }
#pragma unroll
        for (int m = 1; m <= 8; m <<= 1) {
            sum += __shfl_xor(sum, m, 64);
            sq  += __shfl_xor(sq,  m, 64);
        }
        float mu   = sum * 0.015625f;
        float var  = sq * 0.015625f - mu * mu;
        float rstd = rsqrtf(var + 1e-5f);
#pragma unroll
        for (int nt = 0; nt < 4; ++nt) {
            out[base64 + toff + r * 64 + nt * 16] = (px[nt] - mu) * rstd * scl[nt] + bia[nt];
        }
    }
}

extern "C" void kernel_launch(void* const* d_in, const int* in_sizes, int n_in,
                              void* d_out, int out_size, void* d_ws, size_t ws_size,
                              hipStream_t stream) {
    const float* Xq   = (const float*)d_in[0];
    const float* Xk   = (const float*)d_in[1];
    const float* Xv   = (const float*)d_in[2];
    const float* msk  = (const float*)d_in[3];
    const float* res  = (const float*)d_in[4];
    const float* Wq   = (const float*)d_in[5];
    const float* Wk   = (const float*)d_in[6];
    const float* Wv   = (const float*)d_in[7];
    const float* Wfc  = (const float*)d_in[8];
    const float* lnS  = (const float*)d_in[9];
    const float* lnB  = (const float*)d_in[10];
    float* out    = (float*)d_out;
    float* scores = out + OUT_ELEMS;
    mta_kernel<<<BN, 256, 0, stream>>>(Xq, Xk, Xv, msk, res, Wq, Wk, Wv, Wfc,
                                       lnS, lnB, out, scores);
}

// Round 5
// 100.024 us; speedup vs baseline: 2.2374x; 1.8444x over previous
//
#include <hip/hip_runtime.h>

#define B_   8
#define N_   307
#define BN   (B_ * N_)          // 2456 blocks
#define OUT_ELEMS (BN * 64 * 64)

typedef float f32x4 __attribute__((ext_vector_type(4)));
typedef short s16x8 __attribute__((ext_vector_type(8)));

__device__ __forceinline__ unsigned short f2bf(float x) {
    unsigned int u = __builtin_bit_cast(unsigned int, x);
    u += 0x7FFFu + ((u >> 16) & 1u);        // round-to-nearest-even
    return (unsigned short)(u >> 16);
}

// XOR-swizzle on 16B frag rows (G4 / m201): bijective within 8-row groups.
__device__ __forceinline__ int swz(int row) { return row ^ ((row >> 3) & 7); }

__device__ __forceinline__ s16x8 ldfrag(const unsigned short* p) {
    return *reinterpret_cast<const s16x8*>(p);
}

__device__ __forceinline__ s16x8 cvt8(float4 lo, float4 hi) {
    s16x8 f;
    f[0] = (short)f2bf(lo.x); f[1] = (short)f2bf(lo.y);
    f[2] = (short)f2bf(lo.z); f[3] = (short)f2bf(lo.w);
    f[4] = (short)f2bf(hi.x); f[5] = (short)f2bf(hi.y);
    f[6] = (short)f2bf(hi.z); f[7] = (short)f2bf(hi.w);
    return f;
}

// 64x64 row-major fp32 (K x N) global -> bf16 B-operand frag layout (swizzled)
__device__ __forceinline__ void stage_B(const float* __restrict__ src,
                                        unsigned short* dst, int tid) {
    const float4* s4 = reinterpret_cast<const float4*>(src);
#pragma unroll
    for (int i = 0; i < 4; ++i) {
        int idx = i * 256 + tid;
        float4 v = s4[idx];
        int k  = idx >> 4;
        int n0 = (idx & 15) << 2;
        int ki = k >> 5;
        int qd = (k >> 3) & 3;
        int j  = k & 7;
        float vv[4] = {v.x, v.y, v.z, v.w};
#pragma unroll
        for (int c = 0; c < 4; ++c) {
            int n = n0 + c;
            int row = ((n >> 4) * 2 + ki) * 64 + (qd << 4) + (n & 15);
            dst[(swz(row) << 3) + j] = f2bf(vv[c]);
        }
    }
}

__global__ __launch_bounds__(256, 4) void mta_kernel(
    const float* __restrict__ Xq, const float* __restrict__ Xk,
    const float* __restrict__ Xv, const float* __restrict__ maskp,
    const float* __restrict__ res, const float* __restrict__ Wq,
    const float* __restrict__ Wk, const float* __restrict__ Wv,
    const float* __restrict__ Wfc, const float* __restrict__ lnS,
    const float* __restrict__ lnB, float* __restrict__ out,
    float* __restrict__ scores_out)
{
    // 32KB LDS; (256,4) min-occupancy so the allocator has VGPR headroom
    // (hardware can still fit 5 blocks/CU if VGPR <= ~102).
    // q-row-tiled attention (coalesced complete 256B rows, plain cached stores).
    // Softmax: no max-sub (scores bounded; masked -1e9 -> exp underflow 0);
    // cross-wave combine = 1KB column-sum buffer aliased into dead LDS:
    //   head 0   -> sWA first 1KB (extra barrier before frag writes)
    //   head h>0 -> sKf region of head h-1 (dead since h-1's combine barrier)
    __shared__ __align__(16) unsigned char smem[32768];
    unsigned short* sKf = (unsigned short*)(smem);           // 8KB scores B-frags (K)
    unsigned short* sQf = (unsigned short*)(smem + 8192);    // 8KB scores A-frags (Q) / ctx frags (fc)
    unsigned short* sVf = (unsigned short*)(smem + 16384);   // 8KB PV B-frags (V)
    unsigned short* sWA = (unsigned short*)(smem + 24576);   // 8KB W frags / attn A-frags

    const int bn   = blockIdx.x;
    const int tid  = threadIdx.x;
    const int w    = tid >> 6;
    const int lane = tid & 63;
    const int quad = lane >> 4;
    const int l16  = lane & 15;
    const size_t base64 = (size_t)bn * 4096;

    // q-tiled per-lane tile offset: element (q = w*16+quad*4+r, col = nt*16+l16)
    // sits at toff + r*64 + nt*16 (imm-foldable).
    const int toff = (w * 16 + quad * 4) * 64 + l16;

    // mask bits for this thread's 4 q-rows
    float4 mv = *reinterpret_cast<const float4*>(maskp + bn * 64 + w * 16 + quad * 4);
    bool bm[4] = {mv.x > 0.5f, mv.y > 0.5f, mv.z > 0.5f, mv.w > 0.5f};

    // res double-buffer; prefetch head 0 now (lands under projections)
    float rA[4][4], rB[4][4];
    {
        const float* rp = res + (((size_t)(bn * 4)) << 12) + toff;
#pragma unroll
        for (int nt = 0; nt < 4; ++nt)
#pragma unroll
            for (int r = 0; r < 4; ++r)
                rA[nt][r] = rp[r * 64 + nt * 16];
    }

    // ---------------- Projections: Q (scaled 1/4), K, V ----------------
#pragma unroll 1
    for (int pj = 0; pj < 3; ++pj) {
        const float* Xs = (pj == 0) ? Xq : (pj == 1) ? Xk : Xv;
        const float* Ws = (pj == 0) ? Wq : (pj == 1) ? Wk : Wv;
        // A-frags direct from global: lane holds X[m=w*16+l16][k=quad*8+ki*32 ..+7]
        const float* p = Xs + base64 + (w * 16 + l16) * 64 + quad * 8;
        float4 x0 = *(const float4*)(p);      float4 x1 = *(const float4*)(p + 4);
        float4 x2 = *(const float4*)(p + 32); float4 x3 = *(const float4*)(p + 36);
        stage_B(Ws, sWA, tid);
        __syncthreads();
        s16x8 a0 = cvt8(x0, x1);
        s16x8 a1 = cvt8(x2, x3);
#pragma unroll
        for (int nt = 0; nt < 4; ++nt) {
            f32x4 acc = {0.f, 0.f, 0.f, 0.f};
            s16x8 b0 = ldfrag(sWA + (swz((nt * 2 + 0) * 64 + lane) << 3));
            s16x8 b1 = ldfrag(sWA + (swz((nt * 2 + 1) * 64 + lane) << 3));
            acc = __builtin_amdgcn_mfma_f32_16x16x32_bf16(a0, b0, acc, 0, 0, 0);
            acc = __builtin_amdgcn_mfma_f32_16x16x32_bf16(a1, b1, acc, 0, 0, 0);
            if (pj == 0) {          // Q -> scores A-frag layout, fold 1/sqrt(16)
#pragma unroll
                for (int r = 0; r < 4; ++r) {
                    int rowq = (nt * 4 + w) * 32 + ((l16 >> 3) << 4) + quad * 4 + r;
                    sQf[(swz(rowq) << 3) + (l16 & 7)] = f2bf(acc[r] * 0.25f);
                }
            } else if (pj == 1) {   // K -> scores B-frag layout
#pragma unroll
                for (int r = 0; r < 4; ++r) {
                    int rowk = (nt * 4 + w) * 32 + ((l16 >> 3) << 4) + quad * 4 + r;
                    sKf[(swz(rowk) << 3) + (l16 & 7)] = f2bf(acc[r]);
                }
            } else {                // V -> PV B-frag layout (nt == head)
#pragma unroll
                for (int r = 0; r < 4; ++r) {
                    int kk = w * 16 + quad * 4 + r;
                    int rowv = (nt * 2 + (kk >> 5)) * 64 + (((kk >> 3) & 3) << 4) + l16;
                    sVf[(swz(rowv) << 3) + (kk & 7)] = f2bf(acc[r]);
                }
            }
        }
        __syncthreads();
    }

    // ---------------- Attention (q-row-tiled waves; full rows coalesced) ----------------
    f32x4 ctx[4];
#pragma unroll
    for (int h = 0; h < 4; ++h) ctx[h] = {0.f, 0.f, 0.f, 0.f};

    const s16x8 zf = {0, 0, 0, 0, 0, 0, 0, 0};
#pragma unroll
    for (int h = 0; h < 4; ++h) {
        const size_t sbase = ((size_t)(bn * 4 + h)) << 12;
        float (&rc)[4][4] = (h & 1) ? rB : rA;   // current head's res
        float (&rn)[4][4] = (h & 1) ? rA : rB;   // next head's res
        if (h < 3) {
            const float* rp = res + sbase + 4096 + toff;
#pragma unroll
            for (int nt = 0; nt < 4; ++nt)
#pragma unroll
                for (int r = 0; r < 4; ++r)
                    rn[nt][r] = rp[r * 64 + nt * 16];
        }

        // scores tile rows w*16..+15: A = Q tile w, loop B over k-ntiles. K=16 zero-padded.
        s16x8 aq = zf;
        if (lane < 32) aq = ldfrag(sQf + (swz((h * 4 + w) * 32 + lane) << 3));
        float sv[4][4], Sw[4];
#pragma unroll
        for (int nt = 0; nt < 4; ++nt) {
            s16x8 bk = zf;
            if (lane < 32) bk = ldfrag(sKf + (swz((h * 4 + nt) * 32 + lane) << 3));
            f32x4 t = {0.f, 0.f, 0.f, 0.f};
            t = __builtin_amdgcn_mfma_f32_16x16x32_bf16(aq, bk, t, 0, 0, 0);
#pragma unroll
            for (int r = 0; r < 4; ++r) {
                float s = t[r] + rc[nt][r];
                s = bm[r] ? -1e9f : s;
                scores_out[sbase + toff + r * 64 + nt * 16] = s;  // plain cached store
                sv[nt][r] = __expf(s);      // masked rows -> exp underflows to 0
            }
            // per-column (k = nt*16+l16) partial sum over this wave's 16 q rows
            float e = sv[nt][0] + sv[nt][1] + sv[nt][2] + sv[nt][3];
            e += __shfl_xor(e, 16, 64);
            e += __shfl_xor(e, 32, 64);
            Sw[nt] = e;
        }
        float* wS = (h == 0) ? (float*)(smem + 24576) : (float*)(smem + (h - 1) * 2048);
        if (quad == 0) {
#pragma unroll
            for (int nt = 0; nt < 4; ++nt) wS[(nt * 16 + l16) * 4 + w] = Sw[nt];
        }
        __syncthreads();   // combine barrier (also orders prev head's PV reads of sWA)

        float inv[4];
#pragma unroll
        for (int nt = 0; nt < 4; ++nt) {
            float4 vs = *reinterpret_cast<float4*>(&wS[(nt * 16 + l16) * 4]);
            inv[nt] = 1.0f / (vs.x + vs.y + vs.z + vs.w + 1e-30f);
        }
        if (h == 0) __syncthreads();   // wS aliases sWA only at head 0

        // attn -> PV A-frag layout (q = w*16+quad*4+r, k = nt*16+l16)
#pragma unroll
        for (int nt = 0; nt < 4; ++nt) {
            int k  = nt * 16 + l16;
            int rw = (w * 2 + (k >> 5)) * 64 + (((k >> 3) & 3) << 4) + quad * 4;
#pragma unroll
            for (int r = 0; r < 4; ++r)
                sWA[(swz(rw + r) << 3) + (k & 7)] = f2bf(sv[nt][r] * inv[nt]);
        }
        __syncthreads();

        // PV: ctx_h += attn · V_h
#pragma unroll
        for (int ki = 0; ki < 2; ++ki) {
            s16x8 ap = ldfrag(sWA + (swz((w * 2 + ki) * 64 + lane) << 3));
            s16x8 bv = ldfrag(sVf + (swz((h * 2 + ki) * 64 + lane) << 3));
            ctx[h] = __builtin_amdgcn_mfma_f32_16x16x32_bf16(ap, bv, ctx[h], 0, 0, 0);
        }
        // no trailing barrier: next head's combine barrier orders sWA reuse
    }
    __syncthreads();   // protect sWA (Wfc staging) + sQf (ctx frags) after last PV

    // ---------------- fc + residual + layernorm ----------------
    float xres[4][4];
    {
        const float* xp = Xq + base64 + toff;
#pragma unroll
        for (int nt = 0; nt < 4; ++nt)
#pragma unroll
            for (int r = 0; r < 4; ++r)
                xres[nt][r] = xp[r * 64 + nt * 16];
    }
    // ctx -> fc A-frag layout (into sQf, dead after attention)
#pragma unroll
    for (int hh = 0; hh < 4; ++hh) {
        int c    = hh * 16 + l16;
        int rowb = (w * 2 + (c >> 5)) * 64 + (((c >> 3) & 3) << 4) + quad * 4;
#pragma unroll
        for (int r = 0; r < 4; ++r)
            sQf[(swz(rowb + r) << 3) + (c & 7)] = f2bf(ctx[hh][r]);
    }
    stage_B(Wfc, sWA, tid);
    __syncthreads();

    f32x4 oacc[4];
    {
        s16x8 a0 = ldfrag(sQf + (swz((w * 2 + 0) * 64 + lane) << 3));
        s16x8 a1 = ldfrag(sQf + (swz((w * 2 + 1) * 64 + lane) << 3));
#pragma unroll
        for (int nt = 0; nt < 4; ++nt) {
            f32x4 acc = {0.f, 0.f, 0.f, 0.f};
            s16x8 b0 = ldfrag(sWA + (swz((nt * 2 + 0) * 64 + lane) << 3));
            s16x8 b1 = ldfrag(sWA + (swz((nt * 2 + 1) * 64 + lane) << 3));
            acc = __builtin_amdgcn_mfma_f32_16x16x32_bf16(a0, b0, acc, 0, 0, 0);
            acc = __builtin_amdgcn_mfma_f32_16x16x32_bf16(a1, b1, acc, 0, 0, 0);
            oacc[nt] = acc;
        }
    }

    float scl[4], bia[4];
#pragma unroll
    for (int nt = 0; nt < 4; ++nt) {
        scl[nt] = lnS[nt * 16 + l16];
        bia[nt] = lnB[nt * 16 + l16];
    }
#pragma unroll
    for (int r = 0; r < 4; ++r) {
        float px[4], sum = 0.f, sq = 0.f;
#pragma unroll
        for (int nt = 0; nt < 4; ++nt) {
            float x = oacc[nt][r] + xres[nt][r];
            px[nt] = x; sum += x; sq += x * x;
        }
#pragma unroll
        for (int m = 1; m <= 8; m <<= 1) {
            sum += __shfl_xor(sum, m, 64);
            sq  += __shfl_xor(sq,  m, 64);
        }
        float mu   = sum * 0.015625f;
        float var  = sq * 0.015625f - mu * mu;
        float rstd = rsqrtf(var + 1e-5f);
#pragma unroll
        for (int nt = 0; nt < 4; ++nt) {
            out[base64 + toff + r * 64 + nt * 16] = (px[nt] - mu) * rstd * scl[nt] + bia[nt];
        }
    }
}

extern "C" void kernel_launch(void* const* d_in, const int* in_sizes, int n_in,
                              void* d_out, int out_size, void* d_ws, size_t ws_size,
                              hipStream_t stream) {
    const float* Xq   = (const float*)d_in[0];
    const float* Xk   = (const float*)d_in[1];
    const float* Xv   = (const float*)d_in[2];
    const float* msk  = (const float*)d_in[3];
    const float* res  = (const float*)d_in[4];
    const float* Wq   = (const float*)d_in[5];
    const float* Wk   = (const float*)d_in[6];
    const float* Wv   = (const float*)d_in[7];
    const float* Wfc  = (const float*)d_in[8];
    const float* lnS  = (const float*)d_in[9];
    const float* lnB  = (const float*)d_in[10];
    float* out    = (float*)d_out;
    float* scores = out + OUT_ELEMS;
    mta_kernel<<<BN, 256, 0, stream>>>(Xq, Xk, Xv, msk, res, Wq, Wk, Wv, Wfc,
                                       lnS, lnB, out, scores);
}